// Round 1
// baseline (104.939 us; speedup 1.0000x reference)
//
#include <hip/hip_runtime.h>

typedef unsigned short u16;
typedef __attribute__((ext_vector_type(8))) short bf16x8;
typedef __attribute__((ext_vector_type(4))) float f32x4;

__device__ __forceinline__ u16 f2bf(float f) {
  union { float f; unsigned u; } v; v.f = f;
  unsigned u = v.u;
  return (u16)((u + 0x7FFFu + ((u >> 16) & 1u)) >> 16);
}

// ---------------- elementwise f32 -> bf16 (4 per thread) ----------------
__global__ __launch_bounds__(256) void cvt_bf16(const float* __restrict__ in,
                                                u16* __restrict__ out, int n) {
  int i = (blockIdx.x * 256 + threadIdx.x) * 4;
  if (i + 3 < n) {
    float4 f = *(const float4*)(in + i);
    ushort4 r;
    r.x = f2bf(f.x); r.y = f2bf(f.y); r.z = f2bf(f.z); r.w = f2bf(f.w);
    *(ushort4*)(out + i) = r;
  }
}

// ---------------- transpose + convert: in f32 [R][C] -> out bf16 [C][R] ----------------
__global__ __launch_bounds__(256) void tconv(const float* __restrict__ in,
                                             u16* __restrict__ out, int R, int C) {
  __shared__ float t[32][33];
  int c0 = blockIdx.x * 32, r0 = blockIdx.y * 32;
  int tx = threadIdx.x & 31, ty = threadIdx.x >> 5;
  for (int rr = ty; rr < 32; rr += 8)
    t[rr][tx] = in[(size_t)(r0 + rr) * C + c0 + tx];
  __syncthreads();
  for (int rr = ty; rr < 32; rr += 8)
    out[(size_t)(c0 + rr) * R + r0 + tx] = f2bf(t[tx][rr]);
}

// ---------------- bf16 MFMA GEMM: C[M][N] = A[M][K] * BT[N][K]^T + bias ----------------
// 128x128 tile, BK=64, 4 waves (2x2), each wave 64x64 out (4x4 frags of 16x16x32).
// LDS tiles XOR-swizzled at 16B-granule level so ds_read_b128 is bank-balanced.
template<int OUT_BF16>
__global__ __launch_bounds__(256) void gemm_bt(const u16* __restrict__ A,
                                               const u16* __restrict__ BT,
                                               const float* __restrict__ bias,
                                               void* __restrict__ Cp,
                                               int M, int N, int K) {
  __shared__ u16 As[128 * 64];
  __shared__ u16 Bs[128 * 64];
  const int tid = threadIdx.x;
  const int lane = tid & 63, wv = tid >> 6;
  const int lr = lane & 15, lg = lane >> 4;
  const int wm = wv >> 1, wn = wv & 1;
  const int m0 = blockIdx.y * 128, n0 = blockIdx.x * 128;

  f32x4 acc[4][4] = {};

  for (int kt = 0; kt < K; kt += 64) {
    __syncthreads();
    // stage: 1024 granules (16B) each for A and B; LDS slot (r,g) holds global granule (r, g^(r&7))
#pragma unroll
    for (int it = 0; it < 4; ++it) {
      int c = tid + it * 256;
      int r = c >> 3, g = c & 7;
      int gs = g ^ (r & 7);
      *(uint4*)&As[r * 64 + g * 8] = *(const uint4*)&A[(size_t)(m0 + r) * K + kt + gs * 8];
      *(uint4*)&Bs[r * 64 + g * 8] = *(const uint4*)&BT[(size_t)(n0 + r) * K + kt + gs * 8];
    }
    __syncthreads();
#pragma unroll
    for (int ks = 0; ks < 2; ++ks) {
      bf16x8 av[4], bv[4];
#pragma unroll
      for (int m = 0; m < 4; ++m) {
        int r = wm * 64 + m * 16 + lr;
        av[m] = *(const bf16x8*)&As[r * 64 + (((ks * 4 + lg) ^ (r & 7)) * 8)];
      }
#pragma unroll
      for (int n = 0; n < 4; ++n) {
        int r = wn * 64 + n * 16 + lr;
        bv[n] = *(const bf16x8*)&Bs[r * 64 + (((ks * 4 + lg) ^ (r & 7)) * 8)];
      }
#pragma unroll
      for (int m = 0; m < 4; ++m)
#pragma unroll
        for (int n = 0; n < 4; ++n)
          acc[m][n] = __builtin_amdgcn_mfma_f32_16x16x32_bf16(av[m], bv[n], acc[m][n], 0, 0, 0);
    }
  }

#pragma unroll
  for (int m = 0; m < 4; ++m) {
#pragma unroll
    for (int n = 0; n < 4; ++n) {
      int col = n0 + wn * 64 + n * 16 + lr;
      float bcol = bias[col];
#pragma unroll
      for (int qq = 0; qq < 4; ++qq) {
        int row = m0 + wm * 64 + m * 16 + 4 * lg + qq;
        float v = acc[m][n][qq] + bcol;
        if (OUT_BF16) ((u16*)Cp)[(size_t)row * N + col] = f2bf(v);
        else          ((float*)Cp)[(size_t)row * N + col] = v;
      }
    }
  }
}

// ---------------- fused sparse attention ----------------
// grid: (16 heads, 32 row-blocks of 64). qkv bf16 [2048][3072]; out bf16 [2048][1024].
// Active cols per row-block: 192 window cols [i0-64, i0+127] + 64 strided cols (j%32==0),
// strided cols inside the window range masked out of the strided section (no double count).
#define NEGINF (-1e30f)

__global__ __launch_bounds__(256) void sparse_attn(const u16* __restrict__ qkv,
                                                   u16* __restrict__ ao) {
  const int h = blockIdx.x;
  const int i0 = blockIdx.y * 64;
  const int ws = i0 - 64;
  const int tid = threadIdx.x;
  const int lane = tid & 63, wv = tid >> 6;
  const int lr = lane & 15, lg = lane >> 4;

  __shared__ u16 Qs[64][72];    // Q[i][d], pad to 72 (stride 9 granules, odd -> bank-balanced)
  __shared__ u16 Ks[256][72];   // K_sel[jcol][d]
  __shared__ u16 Vt[64][264];   // V_sel^T: [d][jcol], stride 33 granules
  __shared__ u16 Ps[64][264];   // P[i][jcol] bf16
  __shared__ float red[4][64];
  __shared__ float rowmax[64];
  __shared__ float rowsum[64];

  // ---- stage Q (64 rows x 64 d) ----
#pragma unroll
  for (int it = 0; it < 2; ++it) {
    int c = tid + it * 256;
    int r = c >> 3, g = c & 7;
    *(uint4*)&Qs[r][g * 8] = *(const uint4*)&qkv[(size_t)(i0 + r) * 3072 + h * 64 + g * 8];
  }
  // ---- stage K_sel (256 cols x 64 d) ----
#pragma unroll
  for (int it = 0; it < 8; ++it) {
    int c = tid + it * 256;
    int r = c >> 3, g = c & 7;
    int j = (r < 192) ? (ws + r) : ((r - 192) << 5);
    j = j < 0 ? 0 : (j > 2047 ? 2047 : j);
    *(uint4*)&Ks[r][g * 8] = *(const uint4*)&qkv[(size_t)j * 3072 + 1024 + h * 64 + g * 8];
  }
  // ---- stage V_sel transposed ----
#pragma unroll
  for (int it = 0; it < 8; ++it) {
    int c = tid + it * 256;
    int r = c >> 3, g = c & 7;  // r = jcol, g = d-granule
    int j = (r < 192) ? (ws + r) : ((r - 192) << 5);
    j = j < 0 ? 0 : (j > 2047 ? 2047 : j);
    uint4 d4 = *(const uint4*)&qkv[(size_t)j * 3072 + 2048 + h * 64 + g * 8];
    const u16* dv = (const u16*)&d4;
#pragma unroll
    for (int x = 0; x < 8; ++x) {
      int xx = (x + g) & 7;  // stagger by g to spread banks
      Vt[g * 8 + xx][r] = dv[xx];
    }
  }
  __syncthreads();

  // ---- scores: wave wv owns cols [wv*64, wv*64+64), all 64 rows ----
  f32x4 sc[4][4] = {};
#pragma unroll
  for (int ks = 0; ks < 2; ++ks) {
    bf16x8 qa[4];
#pragma unroll
    for (int m = 0; m < 4; ++m)
      qa[m] = *(const bf16x8*)&Qs[m * 16 + lr][ks * 32 + lg * 8];
#pragma unroll
    for (int n = 0; n < 4; ++n) {
      bf16x8 kb = *(const bf16x8*)&Ks[wv * 64 + n * 16 + lr][ks * 32 + lg * 8];
#pragma unroll
      for (int m = 0; m < 4; ++m)
        sc[m][n] = __builtin_amdgcn_mfma_f32_16x16x32_bf16(qa[m], kb, sc[m][n], 0, 0, 0);
    }
  }

  // ---- mask + scale ----
#pragma unroll
  for (int m = 0; m < 4; ++m)
#pragma unroll
    for (int n = 0; n < 4; ++n)
#pragma unroll
      for (int qq = 0; qq < 4; ++qq) {
        int row = m * 16 + 4 * lg + qq;
        int i = i0 + row;
        int cidx = wv * 64 + n * 16 + lr;
        bool ok;
        if (cidx < 192) {
          int j = ws + cidx;
          int dd = i - j; if (dd < 0) dd = -dd;
          ok = (j >= 0) && (j < 2048) && ((dd <= 64) || ((j & 31) == 0));
        } else {
          int j = (cidx - 192) << 5;
          ok = (j < ws) || (j > ws + 191);
        }
        sc[m][n][qq] = ok ? sc[m][n][qq] * 0.125f : NEGINF;
      }

  // ---- row max (over 256 cols): in-lane over n, shuffle over 16 lanes, LDS over waves ----
  float pm[4][4];
#pragma unroll
  for (int m = 0; m < 4; ++m)
#pragma unroll
    for (int qq = 0; qq < 4; ++qq) {
      float v = fmaxf(fmaxf(sc[m][0][qq], sc[m][1][qq]), fmaxf(sc[m][2][qq], sc[m][3][qq]));
      v = fmaxf(v, __shfl_xor(v, 1));
      v = fmaxf(v, __shfl_xor(v, 2));
      v = fmaxf(v, __shfl_xor(v, 4));
      v = fmaxf(v, __shfl_xor(v, 8));
      pm[m][qq] = v;
    }
  if (lr == 0)
#pragma unroll
    for (int m = 0; m < 4; ++m)
#pragma unroll
      for (int qq = 0; qq < 4; ++qq)
        red[wv][m * 16 + 4 * lg + qq] = pm[m][qq];
  __syncthreads();
  if (tid < 64)
    rowmax[tid] = fmaxf(fmaxf(red[0][tid], red[1][tid]), fmaxf(red[2][tid], red[3][tid]));
  __syncthreads();

  // ---- p = exp(s - max); write P bf16; row sums ----
#pragma unroll
  for (int m = 0; m < 4; ++m) {
    float ss[4] = {0.f, 0.f, 0.f, 0.f};
#pragma unroll
    for (int n = 0; n < 4; ++n)
#pragma unroll
      for (int qq = 0; qq < 4; ++qq) {
        int row = m * 16 + 4 * lg + qq;
        float p = __expf(sc[m][n][qq] - rowmax[row]);
        ss[qq] += p;
        Ps[row][wv * 64 + n * 16 + lr] = f2bf(p);
      }
#pragma unroll
    for (int qq = 0; qq < 4; ++qq) {
      float s = ss[qq];
      s += __shfl_xor(s, 1);
      s += __shfl_xor(s, 2);
      s += __shfl_xor(s, 4);
      s += __shfl_xor(s, 8);
      if (lr == 0) red[wv][m * 16 + 4 * lg + qq] = s;
    }
  }
  __syncthreads();
  if (tid < 64)
    rowsum[tid] = red[0][tid] + red[1][tid] + red[2][tid] + red[3][tid];
  __syncthreads();

  // ---- PV: wave wv owns rows [wv*16, wv*16+16), K=256 ----
  f32x4 ov[4] = {};
#pragma unroll
  for (int ks = 0; ks < 8; ++ks) {
    bf16x8 pa = *(const bf16x8*)&Ps[wv * 16 + lr][ks * 32 + lg * 8];
#pragma unroll
    for (int n = 0; n < 4; ++n) {
      bf16x8 vb = *(const bf16x8*)&Vt[n * 16 + lr][ks * 32 + lg * 8];
      ov[n] = __builtin_amdgcn_mfma_f32_16x16x32_bf16(pa, vb, ov[n], 0, 0, 0);
    }
  }
#pragma unroll
  for (int n = 0; n < 4; ++n)
#pragma unroll
    for (int qq = 0; qq < 4; ++qq) {
      int row = wv * 16 + 4 * lg + qq;
      float v = ov[n][qq] / rowsum[row];
      ao[(size_t)(i0 + row) * 1024 + h * 64 + n * 16 + lr] = f2bf(v);
    }
}

// ---------------- launch ----------------
extern "C" void kernel_launch(void* const* d_in, const int* in_sizes, int n_in,
                              void* d_out, int out_size, void* d_ws, size_t ws_size,
                              hipStream_t stream) {
  (void)in_sizes; (void)n_in; (void)out_size; (void)ws_size;
  const float* x     = (const float*)d_in[0];  // [2048][1024]
  const float* w_qkv = (const float*)d_in[1];  // [1024][3072]
  const float* b_qkv = (const float*)d_in[2];  // [3072]
  const float* w_out = (const float*)d_in[3];  // [1024][1024]
  const float* b_out = (const float*)d_in[4];  // [1024]
  float* out = (float*)d_out;                  // [2048][1024] f32
  char* ws = (char*)d_ws;

  u16* xb    = (u16*)(ws);             // 2048*1024*2  = 4,194,304
  u16* wqkvT = (u16*)(ws + 4194304);   // 3072*1024*2  = 6,291,456
  u16* woutT = (u16*)(ws + 10485760);  // 1024*1024*2  = 2,097,152
  u16* qkvb  = (u16*)(ws + 12582912);  // 2048*3072*2  = 12,582,912
  u16* attnb = (u16*)(ws + 25165824);  // 2048*1024*2  = 4,194,304  (end 29,360,128)

  cvt_bf16<<<2048, 256, 0, stream>>>(x, xb, 2048 * 1024);
  tconv<<<dim3(3072 / 32, 1024 / 32), 256, 0, stream>>>(w_qkv, wqkvT, 1024, 3072);
  tconv<<<dim3(1024 / 32, 1024 / 32), 256, 0, stream>>>(w_out, woutT, 1024, 1024);
  gemm_bt<1><<<dim3(3072 / 128, 2048 / 128), 256, 0, stream>>>(xb, wqkvT, b_qkv, qkvb,
                                                               2048, 3072, 1024);
  sparse_attn<<<dim3(16, 32), 256, 0, stream>>>(qkvb, attnb);
  gemm_bt<0><<<dim3(1024 / 128, 2048 / 128), 256, 0, stream>>>(attnb, woutT, b_out, out,
                                                               2048, 1024, 1024);
}

// Round 2
// 84.177 us; speedup vs baseline: 1.2467x; 1.2467x over previous
//
#include <hip/hip_runtime.h>

typedef unsigned short u16;
typedef __attribute__((ext_vector_type(8))) short bf16x8;
typedef __attribute__((ext_vector_type(4))) float f32x4;

__device__ __forceinline__ u16 f2bf(float f) {
  union { float f; unsigned u; } v; v.f = f;
  unsigned u = v.u;
  return (u16)((u + 0x7FFFu + ((u >> 16) & 1u)) >> 16);
}

__device__ __forceinline__ void gld16(const void* g, void* l) {
  __builtin_amdgcn_global_load_lds((const __attribute__((address_space(1))) void*)g,
                                   (__attribute__((address_space(3))) void*)l, 16, 0, 0);
}

// ---------------- elementwise f32 -> bf16 (4 per thread) ----------------
__global__ __launch_bounds__(256) void cvt_bf16(const float* __restrict__ in,
                                                u16* __restrict__ out, int n) {
  int i = (blockIdx.x * 256 + threadIdx.x) * 4;
  if (i + 3 < n) {
    float4 f = *(const float4*)(in + i);
    ushort4 r;
    r.x = f2bf(f.x); r.y = f2bf(f.y); r.z = f2bf(f.z); r.w = f2bf(f.w);
    *(ushort4*)(out + i) = r;
  }
}

// ---------------- transpose + convert: in f32 [R][C] -> out bf16 [C][R] ----------------
__global__ __launch_bounds__(256) void tconv(const float* __restrict__ in,
                                             u16* __restrict__ out, int R, int C) {
  __shared__ float t[32][33];
  int c0 = blockIdx.x * 32, r0 = blockIdx.y * 32;
  int tx = threadIdx.x & 31, ty = threadIdx.x >> 5;
  for (int rr = ty; rr < 32; rr += 8)
    t[rr][tx] = in[(size_t)(r0 + rr) * C + c0 + tx];
  __syncthreads();
  for (int rr = ty; rr < 32; rr += 8)
    out[(size_t)(c0 + rr) * R + r0 + tx] = f2bf(t[tx][rr]);
}

// ---------------- bf16 MFMA GEMM: C[M][N] = A[M][K] * BT[N][K]^T + bias ----------------
// BMx128 tile, BK=64, 4 waves (2x2), wave tile (BM/2)x64. Staging via
// global_load_lds width-16 with pre-swizzled global source (linear LDS dest):
// LDS slot (r,g) holds global granule (r, g^(r&7)) -> ds_read_b128 bank-balanced.
template<int OUT_BF16, int BM>
__global__ __launch_bounds__(256) void gemm_bt(const u16* __restrict__ A,
                                               const u16* __restrict__ BT,
                                               const float* __restrict__ bias,
                                               void* __restrict__ Cp,
                                               int M, int N, int K) {
  constexpr int MT = BM / 32;  // m-frags per wave
  __shared__ u16 As[BM * 64];
  __shared__ u16 Bs[128 * 64];
  const int tid = threadIdx.x;
  const int lane = tid & 63, wv = tid >> 6;
  const int lr = lane & 15, lg = lane >> 4;
  const int wm = wv >> 1, wn = wv & 1;
  const int m0 = blockIdx.y * BM, n0 = blockIdx.x * 128;

  f32x4 acc[MT][4] = {};

  for (int kt = 0; kt < K; kt += 64) {
    __syncthreads();
#pragma unroll
    for (int it = 0; it < MT; ++it) {
      int G = wv * (MT * 64) + it * 64 + lane;
      int r = G >> 3, g = G & 7, gs = g ^ (r & 7);
      gld16(&A[(size_t)(m0 + r) * K + kt + gs * 8], &As[(wv * (MT * 64) + it * 64) * 8]);
    }
#pragma unroll
    for (int it = 0; it < 4; ++it) {
      int G = wv * 256 + it * 64 + lane;
      int r = G >> 3, g = G & 7, gs = g ^ (r & 7);
      gld16(&BT[(size_t)(n0 + r) * K + kt + gs * 8], &Bs[(wv * 256 + it * 64) * 8]);
    }
    __syncthreads();
#pragma unroll
    for (int ks = 0; ks < 2; ++ks) {
      bf16x8 av[MT], bv[4];
#pragma unroll
      for (int m = 0; m < MT; ++m) {
        int r = wm * (BM / 2) + m * 16 + lr;
        av[m] = *(const bf16x8*)&As[r * 64 + (((ks * 4 + lg) ^ (r & 7)) * 8)];
      }
#pragma unroll
      for (int n = 0; n < 4; ++n) {
        int r = wn * 64 + n * 16 + lr;
        bv[n] = *(const bf16x8*)&Bs[r * 64 + (((ks * 4 + lg) ^ (r & 7)) * 8)];
      }
#pragma unroll
      for (int m = 0; m < MT; ++m)
#pragma unroll
        for (int n = 0; n < 4; ++n)
          acc[m][n] = __builtin_amdgcn_mfma_f32_16x16x32_bf16(av[m], bv[n], acc[m][n], 0, 0, 0);
    }
  }

#pragma unroll
  for (int m = 0; m < MT; ++m) {
#pragma unroll
    for (int n = 0; n < 4; ++n) {
      int col = n0 + wn * 64 + n * 16 + lr;
      float bcol = bias[col];
#pragma unroll
      for (int qq = 0; qq < 4; ++qq) {
        int row = m0 + wm * (BM / 2) + m * 16 + 4 * lg + qq;
        float v = acc[m][n][qq] + bcol;
        if (OUT_BF16) ((u16*)Cp)[(size_t)row * N + col] = f2bf(v);
        else          ((float*)Cp)[(size_t)row * N + col] = v;
      }
    }
  }
}

// ---------------- V transpose: qkv[:,2048:3072] -> vT[1024][2048] + packed strided ----
// Block: 256 thr; covers d-span 64 (lane), j-span 32 (wave*8). Reads coalesced
// (64 lanes x u16 contiguous), writes 16B per lane. vTs[d][c] = V[32c][d].
__global__ __launch_bounds__(256) void vtrans(const u16* __restrict__ qkv,
                                              u16* __restrict__ vT,
                                              u16* __restrict__ vTs) {
  const int j0 = blockIdx.x * 32, d0 = blockIdx.y * 64;
  const int lane = threadIdx.x & 63, wv = threadIdx.x >> 6;
  const int d = d0 + lane;
  const int jb = j0 + wv * 8;
  u16 vals[8];
#pragma unroll
  for (int x = 0; x < 8; ++x)
    vals[x] = qkv[(size_t)(jb + x) * 3072 + 2048 + d];
  *(uint4*)&vT[(size_t)d * 2048 + jb] = *(uint4*)vals;
  if (wv == 0)
    vTs[(size_t)d * 64 + (j0 >> 5)] = vals[0];
}

// ---------------- sparse attention: one wave per (head, 16 rows) ----------------
// Cols per block: 144 window (j = ws..ws+143, ws = i0-64) + 64 strided (j=32c,
// excluded when inside window range) = 208, padded to 224 with zero P.
// Q/K frags direct from global (d-contiguous); V frags direct from vT/vTs.
// Only P round-trips through LDS (7.4 KB). All softmax stats in-wave (D-layout
// row = 4*lg+qq identical for QK and PV outputs).
__global__ __launch_bounds__(64) void sattn(const u16* __restrict__ qkv,
                                            const u16* __restrict__ vT,
                                            const u16* __restrict__ vTs,
                                            u16* __restrict__ ao) {
  const int h = blockIdx.x;
  const int i0 = blockIdx.y * 16;
  const int ws = i0 - 64;
  const int lane = threadIdx.x;
  const int lr = lane & 15, lg = lane >> 4;

  __shared__ __attribute__((aligned(16))) u16 Ps[16][232];

  // Q fragments (A-operand: row = lr, k = lg*8 + ks*32)
  const u16* qp = &qkv[(size_t)(i0 + lr) * 3072 + h * 64 + lg * 8];
  bf16x8 qa0 = *(const bf16x8*)qp;
  bf16x8 qa1 = *(const bf16x8*)(qp + 32);

  // K row pointers per n-block (B-operand row = selected col n*16+lr)
  const u16* kp[13];
#pragma unroll
  for (int n = 0; n < 13; ++n) {
    int col = n * 16 + lr;
    int j = (col < 144) ? (ws + col) : ((col - 144) << 5);
    j = j < 0 ? 0 : (j > 2047 ? 2047 : j);
    kp[n] = &qkv[(size_t)j * 3072 + 1024 + h * 64 + lg * 8];
  }

  f32x4 sc[13];
#pragma unroll
  for (int n = 0; n < 13; ++n) {
    bf16x8 k0 = *(const bf16x8*)kp[n];
    bf16x8 k1 = *(const bf16x8*)(kp[n] + 32);
    f32x4 a = {0.f, 0.f, 0.f, 0.f};
    a = __builtin_amdgcn_mfma_f32_16x16x32_bf16(qa0, k0, a, 0, 0, 0);
    a = __builtin_amdgcn_mfma_f32_16x16x32_bf16(qa1, k1, a, 0, 0, 0);
    sc[n] = a;
  }

  // mask + scale + row max
  float mx[4] = {-1e30f, -1e30f, -1e30f, -1e30f};
#pragma unroll
  for (int n = 0; n < 13; ++n) {
    int col = n * 16 + lr;
    int jw = ws + col;
    int js = (col - 144) << 5;
    bool isw = col < 144;
#pragma unroll
    for (int qq = 0; qq < 4; ++qq) {
      int i = i0 + 4 * lg + qq;
      bool ok;
      if (isw) {
        int dd = i - jw; dd = dd < 0 ? -dd : dd;
        ok = (jw >= 0) && (jw < 2048) && ((dd <= 64) || ((jw & 31) == 0));
      } else {
        ok = (js < ws) || (js > ws + 143);
      }
      float v = ok ? sc[n][qq] * 0.125f : -1e30f;
      sc[n][qq] = v;
      mx[qq] = fmaxf(mx[qq], v);
    }
  }
#pragma unroll
  for (int qq = 0; qq < 4; ++qq) {
    float v = mx[qq];
    v = fmaxf(v, __shfl_xor(v, 1));
    v = fmaxf(v, __shfl_xor(v, 2));
    v = fmaxf(v, __shfl_xor(v, 4));
    v = fmaxf(v, __shfl_xor(v, 8));
    mx[qq] = v;
  }

  // exp, row sum, write P to LDS (bf16)
  float sm[4] = {0.f, 0.f, 0.f, 0.f};
#pragma unroll
  for (int n = 0; n < 13; ++n) {
#pragma unroll
    for (int qq = 0; qq < 4; ++qq) {
      float p = __expf(sc[n][qq] - mx[qq]);
      sm[qq] += p;
      Ps[4 * lg + qq][n * 16 + lr] = f2bf(p);
    }
  }
#pragma unroll
  for (int qq = 0; qq < 4; ++qq) {
    float s = sm[qq];
    s += __shfl_xor(s, 1);
    s += __shfl_xor(s, 2);
    s += __shfl_xor(s, 4);
    s += __shfl_xor(s, 8);
    sm[qq] = s;
  }
  // zero-pad P cols 208..223
  {
    ushort4 z; z.x = 0; z.y = 0; z.z = 0; z.w = 0;
    *(ushort4*)&Ps[lane >> 2][208 + (lane & 3) * 4] = z;
  }
  __syncthreads();

  // PV: A = P rows (lr), B = V^T rows d = n*16+lr, contraction over 224 cols
  f32x4 ov[4] = {{0.f,0.f,0.f,0.f},{0.f,0.f,0.f,0.f},{0.f,0.f,0.f,0.f},{0.f,0.f,0.f,0.f}};
#pragma unroll
  for (int ksb = 0; ksb < 7; ++ksb) {
    bf16x8 pa = *(const bf16x8*)&Ps[lr][ksb * 32 + lg * 8];
    int c0 = ksb * 32 + lg * 8;
#pragma unroll
    for (int n = 0; n < 4; ++n) {
      int d = n * 16 + lr;
      const u16* vp;
      if (c0 < 144) {
        int jb = ws + c0;
        jb = jb < 0 ? 0 : (jb > 2040 ? 2040 : jb);
        vp = &vT[(size_t)(h * 64 + d) * 2048 + jb];
      } else if (c0 < 208) {
        vp = &vTs[((size_t)(h * 64 + d) << 6) + (c0 - 144)];
      } else {
        vp = &vTs[(size_t)(h * 64 + d) << 6];  // P=0 there; any finite data ok
      }
      bf16x8 vb = *(const bf16x8*)vp;
      ov[n] = __builtin_amdgcn_mfma_f32_16x16x32_bf16(pa, vb, ov[n], 0, 0, 0);
    }
  }

  // normalize + store (D row = 4*lg+qq matches sm[] ownership)
#pragma unroll
  for (int qq = 0; qq < 4; ++qq) {
    float inv = 1.0f / sm[qq];
    int row = i0 + 4 * lg + qq;
#pragma unroll
    for (int n = 0; n < 4; ++n)
      ao[(size_t)row * 1024 + h * 64 + n * 16 + lr] = f2bf(ov[n][qq] * inv);
  }
}

// ---------------- launch ----------------
extern "C" void kernel_launch(void* const* d_in, const int* in_sizes, int n_in,
                              void* d_out, int out_size, void* d_ws, size_t ws_size,
                              hipStream_t stream) {
  (void)in_sizes; (void)n_in; (void)out_size; (void)ws_size;
  const float* x     = (const float*)d_in[0];  // [2048][1024]
  const float* w_qkv = (const float*)d_in[1];  // [1024][3072]
  const float* b_qkv = (const float*)d_in[2];  // [3072]
  const float* w_out = (const float*)d_in[3];  // [1024][1024]
  const float* b_out = (const float*)d_in[4];  // [1024]
  float* out = (float*)d_out;                  // [2048][1024] f32
  char* ws = (char*)d_ws;

  u16* xb    = (u16*)(ws);             // 2048*1024*2  = 4,194,304
  u16* wqkvT = (u16*)(ws + 4194304);   // 3072*1024*2  = 6,291,456
  u16* woutT = (u16*)(ws + 10485760);  // 1024*1024*2  = 2,097,152
  u16* qkvb  = (u16*)(ws + 12582912);  // 2048*3072*2  = 12,582,912
  u16* attnb = (u16*)(ws + 25165824);  // 2048*1024*2  = 4,194,304  (end 29,360,128)
  // dead after gemm1 -> reuse:
  u16* vT  = xb;                       // 1024*2048*2  = 4,194,304 (exact fit)
  u16* vTs = wqkvT;                    // 1024*64*2    = 131,072

  cvt_bf16<<<2048, 256, 0, stream>>>(x, xb, 2048 * 1024);
  tconv<<<dim3(3072 / 32, 1024 / 32), 256, 0, stream>>>(w_qkv, wqkvT, 1024, 3072);
  tconv<<<dim3(1024 / 32, 1024 / 32), 256, 0, stream>>>(w_out, woutT, 1024, 1024);
  gemm_bt<1, 128><<<dim3(3072 / 128, 2048 / 128), 256, 0, stream>>>(xb, wqkvT, b_qkv, qkvb,
                                                                    2048, 3072, 1024);
  vtrans<<<dim3(2048 / 32, 1024 / 64), 256, 0, stream>>>(qkvb, vT, vTs);
  sattn<<<dim3(16, 128), 64, 0, stream>>>(qkvb, vT, vTs, attnb);
  gemm_bt<0, 64><<<dim3(1024 / 128, 2048 / 64), 256, 0, stream>>>(attnb, woutT, b_out, out,
                                                                  2048, 1024, 1024);
}

// Round 3
// 69.475 us; speedup vs baseline: 1.5105x; 1.2116x over previous
//
#include <hip/hip_runtime.h>

typedef unsigned short u16;
typedef __attribute__((ext_vector_type(8))) short bf16x8;
typedef __attribute__((ext_vector_type(4))) float f32x4;

__device__ __forceinline__ u16 f2bf(float f) {
  union { float f; unsigned u; } v; v.f = f;
  unsigned u = v.u;
  return (u16)((u + 0x7FFFu + ((u >> 16) & 1u)) >> 16);
}

__device__ __forceinline__ void gld16(const void* g, void* l) {
  __builtin_amdgcn_global_load_lds((const __attribute__((address_space(1))) void*)g,
                                   (__attribute__((address_space(3))) void*)l, 16, 0, 0);
}

// ---------------- fused prep: cvt x->bf16 | transpose+cvt w_qkv | w_out ----------------
// tconv64: f32 [R][C] tile (64 rows x 64 cols) -> bf16 out[C][R].
// LDS stride 65 f32: read rows differ by 4 -> bank delta 260 mod 32 = 4 -> 2-way (free).
__device__ __forceinline__ void tconv64(const float* __restrict__ in, u16* __restrict__ out,
                                        int R, int C, int bc, int br, float* t) {
  const int tid = threadIdx.x;
  const int c0 = bc * 64, r0 = br * 64;
  const int hi = tid >> 4, lo = tid & 15;
#pragma unroll
  for (int it = 0; it < 4; ++it) {
    int r = it * 16 + hi;
    float4 f = *(const float4*)&in[(size_t)(r0 + r) * C + c0 + lo * 4];
    float* tr = &t[r * 65 + lo * 4];
    tr[0] = f.x; tr[1] = f.y; tr[2] = f.z; tr[3] = f.w;
  }
  __syncthreads();
#pragma unroll
  for (int it = 0; it < 4; ++it) {
    int cc = it * 16 + hi;
    ushort4 o;
    o.x = f2bf(t[(lo * 4 + 0) * 65 + cc]);
    o.y = f2bf(t[(lo * 4 + 1) * 65 + cc]);
    o.z = f2bf(t[(lo * 4 + 2) * 65 + cc]);
    o.w = f2bf(t[(lo * 4 + 3) * 65 + cc]);
    *(ushort4*)&out[(size_t)(c0 + cc) * R + r0 + lo * 4] = o;
  }
}

__global__ __launch_bounds__(256) void prep(const float* __restrict__ x, u16* __restrict__ xb,
                                            const float* __restrict__ wq, u16* __restrict__ wqT,
                                            const float* __restrict__ wo, u16* __restrict__ woT) {
  __shared__ float t[64 * 65];
  int b = blockIdx.x;
  if (b < 1024) {
    // cvt: 2048*1024 f32 -> bf16, 8 per thread
    int i = (b * 256 + threadIdx.x) * 8;
    float4 f0 = *(const float4*)(x + i);
    float4 f1 = *(const float4*)(x + i + 4);
    ushort4 r0, r1;
    r0.x = f2bf(f0.x); r0.y = f2bf(f0.y); r0.z = f2bf(f0.z); r0.w = f2bf(f0.w);
    r1.x = f2bf(f1.x); r1.y = f2bf(f1.y); r1.z = f2bf(f1.z); r1.w = f2bf(f1.w);
    *(ushort4*)(xb + i) = r0;
    *(ushort4*)(xb + i + 4) = r1;
  } else if (b < 1024 + 768) {
    int b2 = b - 1024;                         // w_qkv: C=3072 -> 48 c-tiles, 16 r-tiles
    tconv64(wq, wqT, 1024, 3072, b2 % 48, b2 / 48, t);
  } else {
    int b3 = b - 1792;                         // w_out: 16 x 16 tiles
    tconv64(wo, woT, 1024, 1024, b3 & 15, b3 >> 4, t);
  }
}

// ---------------- bf16 MFMA GEMM: C[M][N] = A[M][K] * BT[N][K]^T + bias ----------------
// BMxBN tile, BK=64, 4 waves (2x2), wave tile (BM/2)x(BN/2). Staging via
// global_load_lds width-16 with pre-swizzled global source (linear LDS dest):
// LDS slot (r,g) holds global granule (r, g^(r&7)) -> ds_read_b128 bank-balanced.
template<int OUT_BF16, int BM, int BN>
__global__ __launch_bounds__(256) void gemm_bt(const u16* __restrict__ A,
                                               const u16* __restrict__ BT,
                                               const float* __restrict__ bias,
                                               void* __restrict__ Cp,
                                               int M, int N, int K) {
  constexpr int MT = BM / 32;  // m-frags per wave
  constexpr int NT = BN / 32;  // n-frags per wave
  __shared__ u16 As[BM * 64];
  __shared__ u16 Bs[BN * 64];
  const int tid = threadIdx.x;
  const int lane = tid & 63, wv = tid >> 6;
  const int lr = lane & 15, lg = lane >> 4;
  const int wm = wv >> 1, wn = wv & 1;
  const int m0 = blockIdx.y * BM, n0 = blockIdx.x * BN;

  f32x4 acc[MT][NT] = {};

  for (int kt = 0; kt < K; kt += 64) {
    __syncthreads();
#pragma unroll
    for (int it = 0; it < MT; ++it) {
      int G = wv * (MT * 64) + it * 64 + lane;
      int r = G >> 3, g = G & 7, gs = g ^ (r & 7);
      gld16(&A[(size_t)(m0 + r) * K + kt + gs * 8], &As[(wv * (MT * 64) + it * 64) * 8]);
    }
#pragma unroll
    for (int it = 0; it < NT; ++it) {
      int G = wv * (NT * 64) + it * 64 + lane;
      int r = G >> 3, g = G & 7, gs = g ^ (r & 7);
      gld16(&BT[(size_t)(n0 + r) * K + kt + gs * 8], &Bs[(wv * (NT * 64) + it * 64) * 8]);
    }
    __syncthreads();
#pragma unroll
    for (int ks = 0; ks < 2; ++ks) {
      bf16x8 av[MT], bv[NT];
#pragma unroll
      for (int m = 0; m < MT; ++m) {
        int r = wm * (BM / 2) + m * 16 + lr;
        av[m] = *(const bf16x8*)&As[r * 64 + (((ks * 4 + lg) ^ (r & 7)) * 8)];
      }
#pragma unroll
      for (int n = 0; n < NT; ++n) {
        int r = wn * (BN / 2) + n * 16 + lr;
        bv[n] = *(const bf16x8*)&Bs[r * 64 + (((ks * 4 + lg) ^ (r & 7)) * 8)];
      }
#pragma unroll
      for (int m = 0; m < MT; ++m)
#pragma unroll
        for (int n = 0; n < NT; ++n)
          acc[m][n] = __builtin_amdgcn_mfma_f32_16x16x32_bf16(av[m], bv[n], acc[m][n], 0, 0, 0);
    }
  }

#pragma unroll
  for (int m = 0; m < MT; ++m) {
#pragma unroll
    for (int n = 0; n < NT; ++n) {
      int col = n0 + wn * (BN / 2) + n * 16 + lr;
      float bcol = bias[col];
#pragma unroll
      for (int qq = 0; qq < 4; ++qq) {
        int row = m0 + wm * (BM / 2) + m * 16 + 4 * lg + qq;
        float v = acc[m][n][qq] + bcol;
        if (OUT_BF16) ((u16*)Cp)[(size_t)row * N + col] = f2bf(v);
        else          ((float*)Cp)[(size_t)row * N + col] = v;
      }
    }
  }
}

// ---------------- V transpose: qkv[:,2048:3072] -> vT[1024][2048] + packed strided ----
__global__ __launch_bounds__(256) void vtrans(const u16* __restrict__ qkv,
                                              u16* __restrict__ vT,
                                              u16* __restrict__ vTs) {
  const int j0 = blockIdx.x * 32, d0 = blockIdx.y * 64;
  const int lane = threadIdx.x & 63, wv = threadIdx.x >> 6;
  const int d = d0 + lane;
  const int jb = j0 + wv * 8;
  u16 vals[8];
#pragma unroll
  for (int x = 0; x < 8; ++x)
    vals[x] = qkv[(size_t)(jb + x) * 3072 + 2048 + d];
  *(uint4*)&vT[(size_t)d * 2048 + jb] = *(uint4*)vals;
  if (wv == 0)
    vTs[(size_t)d * 64 + (j0 >> 5)] = vals[0];
}

// ---------------- sparse attention: one wave per (head, 16 rows) ----------------
__global__ __launch_bounds__(64) void sattn(const u16* __restrict__ qkv,
                                            const u16* __restrict__ vT,
                                            const u16* __restrict__ vTs,
                                            u16* __restrict__ ao) {
  const int h = blockIdx.x;
  const int i0 = blockIdx.y * 16;
  const int ws = i0 - 64;
  const int lane = threadIdx.x;
  const int lr = lane & 15, lg = lane >> 4;

  __shared__ __attribute__((aligned(16))) u16 Ps[16][232];

  const u16* qp = &qkv[(size_t)(i0 + lr) * 3072 + h * 64 + lg * 8];
  bf16x8 qa0 = *(const bf16x8*)qp;
  bf16x8 qa1 = *(const bf16x8*)(qp + 32);

  const u16* kp[13];
#pragma unroll
  for (int n = 0; n < 13; ++n) {
    int col = n * 16 + lr;
    int j = (col < 144) ? (ws + col) : ((col - 144) << 5);
    j = j < 0 ? 0 : (j > 2047 ? 2047 : j);
    kp[n] = &qkv[(size_t)j * 3072 + 1024 + h * 64 + lg * 8];
  }

  f32x4 sc[13];
#pragma unroll
  for (int n = 0; n < 13; ++n) {
    bf16x8 k0 = *(const bf16x8*)kp[n];
    bf16x8 k1 = *(const bf16x8*)(kp[n] + 32);
    f32x4 a = {0.f, 0.f, 0.f, 0.f};
    a = __builtin_amdgcn_mfma_f32_16x16x32_bf16(qa0, k0, a, 0, 0, 0);
    a = __builtin_amdgcn_mfma_f32_16x16x32_bf16(qa1, k1, a, 0, 0, 0);
    sc[n] = a;
  }

  float mx[4] = {-1e30f, -1e30f, -1e30f, -1e30f};
#pragma unroll
  for (int n = 0; n < 13; ++n) {
    int col = n * 16 + lr;
    int jw = ws + col;
    int js = (col - 144) << 5;
    bool isw = col < 144;
#pragma unroll
    for (int qq = 0; qq < 4; ++qq) {
      int i = i0 + 4 * lg + qq;
      bool ok;
      if (isw) {
        int dd = i - jw; dd = dd < 0 ? -dd : dd;
        ok = (jw >= 0) && (jw < 2048) && ((dd <= 64) || ((jw & 31) == 0));
      } else {
        ok = (js < ws) || (js > ws + 143);
      }
      float v = ok ? sc[n][qq] * 0.125f : -1e30f;
      sc[n][qq] = v;
      mx[qq] = fmaxf(mx[qq], v);
    }
  }
#pragma unroll
  for (int qq = 0; qq < 4; ++qq) {
    float v = mx[qq];
    v = fmaxf(v, __shfl_xor(v, 1));
    v = fmaxf(v, __shfl_xor(v, 2));
    v = fmaxf(v, __shfl_xor(v, 4));
    v = fmaxf(v, __shfl_xor(v, 8));
    mx[qq] = v;
  }

  float sm[4] = {0.f, 0.f, 0.f, 0.f};
#pragma unroll
  for (int n = 0; n < 13; ++n) {
#pragma unroll
    for (int qq = 0; qq < 4; ++qq) {
      float p = __expf(sc[n][qq] - mx[qq]);
      sm[qq] += p;
      Ps[4 * lg + qq][n * 16 + lr] = f2bf(p);
    }
  }
#pragma unroll
  for (int qq = 0; qq < 4; ++qq) {
    float s = sm[qq];
    s += __shfl_xor(s, 1);
    s += __shfl_xor(s, 2);
    s += __shfl_xor(s, 4);
    s += __shfl_xor(s, 8);
    sm[qq] = s;
  }
  {
    ushort4 z; z.x = 0; z.y = 0; z.z = 0; z.w = 0;
    *(ushort4*)&Ps[lane >> 2][208 + (lane & 3) * 4] = z;
  }
  __syncthreads();

  f32x4 ov[4] = {{0.f,0.f,0.f,0.f},{0.f,0.f,0.f,0.f},{0.f,0.f,0.f,0.f},{0.f,0.f,0.f,0.f}};
#pragma unroll
  for (int ksb = 0; ksb < 7; ++ksb) {
    bf16x8 pa = *(const bf16x8*)&Ps[lr][ksb * 32 + lg * 8];
    int c0 = ksb * 32 + lg * 8;
#pragma unroll
    for (int n = 0; n < 4; ++n) {
      int d = n * 16 + lr;
      const u16* vp;
      if (c0 < 144) {
        int jb = ws + c0;
        jb = jb < 0 ? 0 : (jb > 2040 ? 2040 : jb);
        vp = &vT[(size_t)(h * 64 + d) * 2048 + jb];
      } else if (c0 < 208) {
        vp = &vTs[((size_t)(h * 64 + d) << 6) + (c0 - 144)];
      } else {
        vp = &vTs[(size_t)(h * 64 + d) << 6];
      }
      bf16x8 vb = *(const bf16x8*)vp;
      ov[n] = __builtin_amdgcn_mfma_f32_16x16x32_bf16(pa, vb, ov[n], 0, 0, 0);
    }
  }

#pragma unroll
  for (int qq = 0; qq < 4; ++qq) {
    float inv = 1.0f / sm[qq];
    int row = i0 + 4 * lg + qq;
#pragma unroll
    for (int n = 0; n < 4; ++n)
      ao[(size_t)row * 1024 + h * 64 + n * 16 + lr] = f2bf(ov[n][qq] * inv);
  }
}

// ---------------- launch ----------------
extern "C" void kernel_launch(void* const* d_in, const int* in_sizes, int n_in,
                              void* d_out, int out_size, void* d_ws, size_t ws_size,
                              hipStream_t stream) {
  (void)in_sizes; (void)n_in; (void)out_size; (void)ws_size;
  const float* x     = (const float*)d_in[0];  // [2048][1024]
  const float* w_qkv = (const float*)d_in[1];  // [1024][3072]
  const float* b_qkv = (const float*)d_in[2];  // [3072]
  const float* w_out = (const float*)d_in[3];  // [1024][1024]
  const float* b_out = (const float*)d_in[4];  // [1024]
  float* out = (float*)d_out;                  // [2048][1024] f32
  char* ws = (char*)d_ws;

  u16* xb    = (u16*)(ws);             // 2048*1024*2  = 4,194,304
  u16* wqkvT = (u16*)(ws + 4194304);   // 3072*1024*2  = 6,291,456
  u16* woutT = (u16*)(ws + 10485760);  // 1024*1024*2  = 2,097,152
  u16* qkvb  = (u16*)(ws + 12582912);  // 2048*3072*2  = 12,582,912
  u16* attnb = (u16*)(ws + 25165824);  // 2048*1024*2  = 4,194,304  (end 29,360,128)
  // dead after gemm1 -> reuse:
  u16* vT  = xb;                       // 1024*2048*2  = 4,194,304 (exact fit)
  u16* vTs = wqkvT;                    // 1024*64*2    = 131,072

  prep<<<2048, 256, 0, stream>>>(x, xb, w_qkv, wqkvT, w_out, woutT);
  gemm_bt<1, 128, 64><<<dim3(3072 / 64, 2048 / 128), 256, 0, stream>>>(xb, wqkvT, b_qkv, qkvb,
                                                                       2048, 3072, 1024);
  vtrans<<<dim3(2048 / 32, 1024 / 64), 256, 0, stream>>>(qkvb, vT, vTs);
  sattn<<<dim3(16, 128), 64, 0, stream>>>(qkvb, vT, vTs, attnb);
  gemm_bt<0, 64, 64><<<dim3(1024 / 64, 2048 / 64), 256, 0, stream>>>(attnb, woutT, b_out, out,
                                                                     2048, 1024, 1024);
}